// Round 1
// baseline (922.814 us; speedup 1.0000x reference)
//
#include <hip/hip_runtime.h>

// Batched matrix exponential of symmetrized 64x64 fp32 matrices.
// exp(S) with S = 0.5*(X + X^T), via scaling-and-squaring:
//   T = S / 2^4, E = Taylor_12(T) (Horner), result = E^(2^4).
// One 256-thread block per matrix; each thread computes a 4x4 output tile.
// All intermediates are polynomials in T => symmetric => A-operand is read
// row-wise (A[k][r] == A[r][k]) so both LDS reads are conflict-free.

constexpr int N = 64;

__global__ __launch_bounds__(256, 3) void expm64_kernel(const float* __restrict__ X,
                                                        float* __restrict__ out) {
    __shared__ float Tm[N * N];   // scaled symmetric input (constant through Horner)
    __shared__ float Pm[N * N];   // ping
    __shared__ float Qm[N * N];   // pong

    const int t = threadIdx.x;
    const size_t base = (size_t)blockIdx.x * (N * N);

    // ---- 1) load X into Pm (coalesced float4: 1024 float4 / 256 threads) ----
    {
        const float4* src = reinterpret_cast<const float4*>(X + base);
        float4* dst = reinterpret_cast<float4*>(Pm);
        #pragma unroll
        for (int i = 0; i < 4; ++i) dst[t + 256 * i] = src[t + 256 * i];
    }
    __syncthreads();

    const int r0 = (t >> 4) << 2;   // row tile base: 0,4,...,60
    const int c0 = (t & 15) << 2;   // col tile base: 0,4,...,60

    // ---- 2) Tm = (X + X^T) * (1/32)  == 0.5*(X+X^T) / 2^4 (exactly symmetric) ----
    {
        const float sc = 1.0f / 32.0f;
        #pragma unroll
        for (int i = 0; i < 4; ++i)
            #pragma unroll
            for (int j = 0; j < 4; ++j) {
                const int r = r0 + i, c = c0 + j;
                Tm[r * N + c] = (Pm[r * N + c] + Pm[c * N + r]) * sc;
            }
    }
    __syncthreads();

    // ---- 3) R0 = I + Tm/12  (into Pm) ----
    {
        const float s12 = 1.0f / 12.0f;
        #pragma unroll
        for (int i = 0; i < 4; ++i)
            #pragma unroll
            for (int j = 0; j < 4; ++j) {
                const int r = r0 + i, c = c0 + j;
                Pm[r * N + c] = Tm[r * N + c] * s12 + ((r == c) ? 1.0f : 0.0f);
            }
    }
    __syncthreads();

    float* Rin = Pm;
    float* Rout = Qm;

    const int ar = r0 >> 2;  // float4 index of this thread's A columns
    const int bc = c0 >> 2;  // float4 index of this thread's B columns

    // ---- 4) 11 Horner stages (k = 11..1), then 4 squarings ----
    for (int stage = 0; stage < 15; ++stage) {
        const bool horner = (stage < 11);
        const float* A = horner ? Tm : Rin;   // symmetric multiplier
        const float* B = Rin;

        float acc[4][4];
        #pragma unroll
        for (int i = 0; i < 4; ++i)
            #pragma unroll
            for (int j = 0; j < 4; ++j) acc[i][j] = 0.0f;

        const float4* A4 = reinterpret_cast<const float4*>(A);
        const float4* B4 = reinterpret_cast<const float4*>(B);

        #pragma unroll 8
        for (int k = 0; k < N; ++k) {
            // A[k][r0..r0+3] (== A[r0..r0+3][k] by symmetry) : 4 distinct b128
            // addrs per wave, 16-lane broadcast, disjoint banks -> conflict-free.
            const float4 a = A4[k * 16 + ar];
            // B[k][c0..c0+3] : full 256B row per wave -> 2-way alias (free).
            const float4 b = B4[k * 16 + bc];
            acc[0][0] += a.x * b.x; acc[0][1] += a.x * b.y; acc[0][2] += a.x * b.z; acc[0][3] += a.x * b.w;
            acc[1][0] += a.y * b.x; acc[1][1] += a.y * b.y; acc[1][2] += a.y * b.z; acc[1][3] += a.y * b.w;
            acc[2][0] += a.z * b.x; acc[2][1] += a.z * b.y; acc[2][2] += a.z * b.z; acc[2][3] += a.z * b.w;
            acc[3][0] += a.w * b.x; acc[3][1] += a.w * b.y; acc[3][2] += a.w * b.z; acc[3][3] += a.w * b.w;
        }

        if (horner) {
            const float invk = 1.0f / (float)(11 - stage);   // k = 11,10,...,1
            #pragma unroll
            for (int i = 0; i < 4; ++i)
                #pragma unroll
                for (int j = 0; j < 4; ++j) {
                    const int r = r0 + i, c = c0 + j;
                    Rout[r * N + c] = acc[i][j] * invk + ((r == c) ? 1.0f : 0.0f);
                }
        } else {
            #pragma unroll
            for (int i = 0; i < 4; ++i)
                #pragma unroll
                for (int j = 0; j < 4; ++j)
                    Rout[(r0 + i) * N + (c0 + j)] = acc[i][j];
        }

        float* tmp = Rin; Rin = Rout; Rout = tmp;
        __syncthreads();
    }

    // ---- 5) store result (Rin) coalesced ----
    {
        const float4* src = reinterpret_cast<const float4*>(Rin);
        float4* dst = reinterpret_cast<float4*>(out + base);
        #pragma unroll
        for (int i = 0; i < 4; ++i) dst[t + 256 * i] = src[t + 256 * i];
    }
}

extern "C" void kernel_launch(void* const* d_in, const int* in_sizes, int n_in,
                              void* d_out, int out_size, void* d_ws, size_t ws_size,
                              hipStream_t stream) {
    const float* X = (const float*)d_in[0];
    float* out = (float*)d_out;
    const int batch = in_sizes[0] / (N * N);   // 8192
    expm64_kernel<<<dim3(batch), dim3(256), 0, stream>>>(X, out);
}

// Round 2
// 693.459 us; speedup vs baseline: 1.3307x; 1.3307x over previous
//
#include <hip/hip_runtime.h>

// Batched matrix exponential of symmetrized 64x64 fp32 matrices.
// exp(S), S = 0.5*(X + X^T), via scaling-and-squaring (s=4) + degree-11
// Taylor evaluated with Paterson-Stockmeyer chunk-2:
//   p(T) = sum_{i=0..5} (c_{2i} I + c_{2i+1} T) (T^2)^i   (Horner in T^2)
// Matmuls: 1 (T^2) + 5 (Horner) + 4 (squarings) = 10  (was 15).
// LDS: T, T2, P = 48 KB -> 3 blocks/CU (12 waves/CU), matching the measured
// 77% VALUBusy regime. P is updated in place (acc in regs, sync, write).
// All left operands are polynomials in T => symmetric => A-operand read
// row-wise (A[k][r] == A[r][k]): 4-address 16-lane-broadcast, conflict-free.

constexpr int N = 64;

__device__ __forceinline__ void mm_tile(const float* __restrict__ A,
                                        const float* __restrict__ B,
                                        int ar, int bc, float acc[4][4]) {
    const float4* A4 = reinterpret_cast<const float4*>(A);
    const float4* B4 = reinterpret_cast<const float4*>(B);
    #pragma unroll
    for (int i = 0; i < 4; ++i)
        #pragma unroll
        for (int j = 0; j < 4; ++j) acc[i][j] = 0.0f;
    #pragma unroll 8
    for (int k = 0; k < N; ++k) {
        const float4 a = A4[k * 16 + ar];   // A[k][r0..r0+3] == A[r0..r0+3][k]
        const float4 b = B4[k * 16 + bc];   // B[k][c0..c0+3]
        acc[0][0] += a.x * b.x; acc[0][1] += a.x * b.y; acc[0][2] += a.x * b.z; acc[0][3] += a.x * b.w;
        acc[1][0] += a.y * b.x; acc[1][1] += a.y * b.y; acc[1][2] += a.y * b.z; acc[1][3] += a.y * b.w;
        acc[2][0] += a.z * b.x; acc[2][1] += a.z * b.y; acc[2][2] += a.z * b.z; acc[2][3] += a.z * b.w;
        acc[3][0] += a.w * b.x; acc[3][1] += a.w * b.y; acc[3][2] += a.w * b.z; acc[3][3] += a.w * b.w;
    }
}

__global__ __launch_bounds__(256, 3) void expm64_kernel(const float* __restrict__ X,
                                                        float* __restrict__ out) {
    __shared__ float Tm[N * N];   // T = S / 16 (symmetric, constant)
    __shared__ float T2[N * N];   // T^2 (also temp for the X load)
    __shared__ float Pm[N * N];   // PS accumulator, updated in place

    const int t = threadIdx.x;
    const size_t base = (size_t)blockIdx.x * (N * N);
    const int r0 = (t >> 4) << 2;   // row tile base
    const int c0 = (t & 15) << 2;   // col tile base
    const int ar = r0 >> 2;
    const int bc = c0 >> 2;

    // ---- load X into T2 (temp), coalesced float4 ----
    {
        const float4* src = reinterpret_cast<const float4*>(X + base);
        float4* dst = reinterpret_cast<float4*>(T2);
        #pragma unroll
        for (int i = 0; i < 4; ++i) dst[t + 256 * i] = src[t + 256 * i];
    }
    __syncthreads();

    // ---- Tm = (X + X^T) * (1/32)  == 0.5*(X+X^T) / 2^4 (exactly symmetric) ----
    {
        const float sc = 1.0f / 32.0f;
        #pragma unroll
        for (int i = 0; i < 4; ++i)
            #pragma unroll
            for (int j = 0; j < 4; ++j) {
                const int r = r0 + i, c = c0 + j;
                Tm[r * N + c] = (T2[r * N + c] + T2[c * N + r]) * sc;
            }
    }
    __syncthreads();

    // ---- T2 = Tm*Tm ; Pm = c10*I + c11*Tm ----
    {
        float acc[4][4];
        mm_tile(Tm, Tm, ar, bc, acc);       // old T2 (X copy) is dead: safe to overwrite
        const float c10 = 2.755731922398589e-07f;   // 1/10!
        const float c11 = 2.505210838544172e-08f;   // 1/11!
        #pragma unroll
        for (int i = 0; i < 4; ++i)
            #pragma unroll
            for (int j = 0; j < 4; ++j) {
                const int r = r0 + i, c = c0 + j;
                T2[r * N + c] = acc[i][j];
                Pm[r * N + c] = c11 * Tm[r * N + c] + ((r == c) ? c10 : 0.0f);
            }
    }
    __syncthreads();

    // ---- 5 Horner stages in T^2:  P = P*T2 + (ce[s]*I + co[s]*T) ----
    {
        // s = 4..0 : (c8,c9) (c6,c7) (c4,c5) (c2,c3) (c0,c1)
        const float ce[5] = { 2.48015873015873e-05f,   // 1/8!
                              1.388888888888889e-03f,  // 1/6!
                              4.1666666666666664e-02f, // 1/4!
                              0.5f,                    // 1/2!
                              1.0f };                  // 1/0!
        const float co[5] = { 2.7557319223985893e-06f, // 1/9!
                              1.984126984126984e-04f,  // 1/7!
                              8.333333333333333e-03f,  // 1/5!
                              1.6666666666666666e-01f, // 1/3!
                              1.0f };                  // 1/1!
        for (int s = 0; s < 5; ++s) {
            float acc[4][4];
            mm_tile(Pm, T2, ar, bc, acc);   // Pm symmetric (polynomial in T)
            __syncthreads();                // all reads of Pm complete
            #pragma unroll
            for (int i = 0; i < 4; ++i)
                #pragma unroll
                for (int j = 0; j < 4; ++j) {
                    const int r = r0 + i, c = c0 + j;
                    Pm[r * N + c] = acc[i][j] + co[s] * Tm[r * N + c]
                                             + ((r == c) ? ce[s] : 0.0f);
                }
            __syncthreads();
        }
    }

    // ---- 4 squarings in place: P = P*P ----
    for (int s = 0; s < 4; ++s) {
        float acc[4][4];
        mm_tile(Pm, Pm, ar, bc, acc);
        __syncthreads();
        #pragma unroll
        for (int i = 0; i < 4; ++i)
            #pragma unroll
            for (int j = 0; j < 4; ++j)
                Pm[(r0 + i) * N + (c0 + j)] = acc[i][j];
        __syncthreads();
    }

    // ---- store result coalesced ----
    {
        const float4* src = reinterpret_cast<const float4*>(Pm);
        float4* dst = reinterpret_cast<float4*>(out + base);
        #pragma unroll
        for (int i = 0; i < 4; ++i) dst[t + 256 * i] = src[t + 256 * i];
    }
}

extern "C" void kernel_launch(void* const* d_in, const int* in_sizes, int n_in,
                              void* d_out, int out_size, void* d_ws, size_t ws_size,
                              hipStream_t stream) {
    const float* X = (const float*)d_in[0];
    float* out = (float*)d_out;
    const int batch = in_sizes[0] / (N * N);   // 8192
    expm64_kernel<<<dim3(batch), dim3(256), 0, stream>>>(X, out);
}

// Round 6
// 353.780 us; speedup vs baseline: 2.6084x; 1.9601x over previous
//
#include <hip/hip_runtime.h>

// Batched expm of symmetrized 64x64 fp32 matrices via scaling-and-squaring
// (s=4, degree-11 Taylor, Paterson-Stockmeyer chunk-2), with matmuls on the
// MFMA pipe using fp16 2-way-split emulation of fp32:
//   x = hi + lo/2048 (hi,lo fp16; lo stored pre-scaled by 2048)
//   A*B = Ah*Bh + (Ah*Bl' + Al'*Bh)/2048 + (Al'*Bl')/2048^2   (8 MFMAs/tile)
// All operands are symmetric (polynomials in T), so:
//   - B-fragment == A-fragment read pattern (contiguous ds_read_b128)
//   - MFMA C column-strips are written TRANSPOSED => contiguous writes
// fp16 planes [64][64] are XOR-swizzled: byte ^= (row&7)<<4 (bank-conflict fix).
// Range: last Taylor stage folds *0.5 => Q=P/2; out = Q^16 * 65536 (exact pow2).

typedef _Float16 half4v __attribute__((ext_vector_type(4)));
typedef _Float16 half8v __attribute__((ext_vector_type(8)));
typedef float f32x4 __attribute__((ext_vector_type(4)));

constexpr int N = 64;

struct Split { _Float16 h, l; };

__device__ __forceinline__ Split split16(float v) {
    Split s;
    s.h = (_Float16)v;
    s.l = (_Float16)((v - (float)s.h) * 2048.0f);
    return s;
}

__device__ __forceinline__ int swz(int row, int colbyte) {
    return (row * 128 + colbyte) ^ ((row & 7) << 4);
}

// A-frag (and, by symmetry, B-frag): lane reads M[tile*16 + lane%16][k0..k0+7],
// k0 = ks*32 + (lane/16)*8  -> one 16B ds_read_b128 (swizzled).
__device__ __forceinline__ half8v frag16(const char* p, int tile, int ks, int lane) {
    const int row = tile * 16 + (lane & 15);
    const int cb = (ks * 32 + ((lane >> 4) << 3)) * 2;
    return *reinterpret_cast<const half8v*>(p + swz(row, cb));
}

// 8-MFMA split product over K=64 (2 ksteps) for one 16x16 C tile.
__device__ __forceinline__ f32x4 mm_split(const half8v* ah, const half8v* al,
                                          const half8v* bh, const half8v* bl) {
    f32x4 c = {0.f, 0.f, 0.f, 0.f};
    c = __builtin_amdgcn_mfma_f32_16x16x32_f16(al[0], bl[0], c, 0, 0, 0);  // lo*lo (2^22)
    c = __builtin_amdgcn_mfma_f32_16x16x32_f16(al[1], bl[1], c, 0, 0, 0);
    #pragma unroll
    for (int e = 0; e < 4; ++e) c[e] *= (1.0f / 2048.0f);                  // -> 2^11
    c = __builtin_amdgcn_mfma_f32_16x16x32_f16(al[0], bh[0], c, 0, 0, 0);  // cross (2^11)
    c = __builtin_amdgcn_mfma_f32_16x16x32_f16(al[1], bh[1], c, 0, 0, 0);
    c = __builtin_amdgcn_mfma_f32_16x16x32_f16(ah[0], bl[0], c, 0, 0, 0);
    c = __builtin_amdgcn_mfma_f32_16x16x32_f16(ah[1], bl[1], c, 0, 0, 0);
    #pragma unroll
    for (int e = 0; e < 4; ++e) c[e] *= (1.0f / 2048.0f);                  // -> 1
    c = __builtin_amdgcn_mfma_f32_16x16x32_f16(ah[0], bh[0], c, 0, 0, 0);  // hi*hi
    c = __builtin_amdgcn_mfma_f32_16x16x32_f16(ah[1], bh[1], c, 0, 0, 0);
    return c;
}

__global__ __launch_bounds__(256, 3) void expm64_kernel(const float* __restrict__ X,
                                                        float* __restrict__ out) {
    __shared__ alignas(16) char lds[49152];
    char* Th = lds;            // T hi plane   (8 KB each)
    char* Tl = lds + 8192;     // T lo
    char* Ph = lds + 16384;    // P hi
    char* Pl = lds + 24576;    // P lo
    char* Qh = lds + 32768;    // T2 hi
    char* Ql = lds + 40960;    // T2 lo
    float* Xs = reinterpret_cast<float*>(lds + 16384);  // fp32 X staging over Ph/Pl

    const int t = threadIdx.x;
    const int lane = t & 63;
    const int wv = t >> 6;          // wave 0..3
    const int wr = (wv >> 1) << 1;  // rowtile base (0 or 2)
    const int wc = (wv & 1) << 1;   // coltile base (0 or 2)
    const size_t base = (size_t)blockIdx.x * (N * N);

    // ---- load X (fp32) coalesced into staging ----
    {
        const float4* src = reinterpret_cast<const float4*>(X + base);
        float4* dst = reinterpret_cast<float4*>(Xs);
        #pragma unroll
        for (int i = 0; i < 4; ++i) dst[t + 256 * i] = src[t + 256 * i];
    }
    __syncthreads();

    const int r0 = (t >> 4) << 2;
    const int c0 = (t & 15) << 2;

    // ---- T = (X + X^T)/32, split -> Th/Tl; keep fp32 in regs ----
    float tv[4][4];
    #pragma unroll
    for (int i = 0; i < 4; ++i) {
        half4v h, l;
        #pragma unroll
        for (int j = 0; j < 4; ++j) {
            float v = (Xs[(r0 + i) * 64 + (c0 + j)] + Xs[(c0 + j) * 64 + (r0 + i)]) * (1.0f / 32.0f);
            tv[i][j] = v;
            Split s = split16(v);
            h[j] = s.h; l[j] = s.l;
        }
        *reinterpret_cast<half4v*>(Th + swz(r0 + i, c0 * 2)) = h;
        *reinterpret_cast<half4v*>(Tl + swz(r0 + i, c0 * 2)) = l;
    }
    __syncthreads();   // X consumed, T planes complete

    // ---- P0 = c10*I + c11*T -> Ph/Pl (overwrites X staging) ----
    {
        const float c10 = 2.755731922398589e-07f;   // 1/10!
        const float c11 = 2.505210838544172e-08f;   // 1/11!
        #pragma unroll
        for (int i = 0; i < 4; ++i) {
            half4v h, l;
            #pragma unroll
            for (int j = 0; j < 4; ++j) {
                float v = c11 * tv[i][j] + ((r0 + i == c0 + j) ? c10 : 0.0f);
                Split s = split16(v);
                h[j] = s.h; l[j] = s.l;
            }
            *reinterpret_cast<half4v*>(Ph + swz(r0 + i, c0 * 2)) = h;
            *reinterpret_cast<half4v*>(Pl + swz(r0 + i, c0 * 2)) = l;
        }
    }
    __syncthreads();

    // ---- stage 1: T2 = T*T  -> Qh/Ql (write arena != read arena: 1 barrier) ----
    {
        half8v ah[2][2], al[2][2], bh[2][2], bl[2][2];
        #pragma unroll
        for (int a = 0; a < 2; ++a)
            #pragma unroll
            for (int ks = 0; ks < 2; ++ks) {
                ah[a][ks] = frag16(Th, wr + a, ks, lane);
                al[a][ks] = frag16(Tl, wr + a, ks, lane);
                bh[a][ks] = frag16(Th, wc + a, ks, lane);
                bl[a][ks] = frag16(Tl, wc + a, ks, lane);
            }
        #pragma unroll
        for (int a = 0; a < 2; ++a)
            #pragma unroll
            for (int b = 0; b < 2; ++b) {
                f32x4 acc = mm_split(ah[a], al[a], bh[b], bl[b]);
                const int rowp = (wc + b) * 16 + (lane & 15);          // transposed
                const int colp = (wr + a) * 16 + ((lane >> 4) << 2);
                half4v h, l;
                #pragma unroll
                for (int e = 0; e < 4; ++e) {
                    Split s = split16(acc[e]);
                    h[e] = s.h; l[e] = s.l;
                }
                *reinterpret_cast<half4v*>(Qh + swz(rowp, colp * 2)) = h;
                *reinterpret_cast<half4v*>(Ql + swz(rowp, colp * 2)) = l;
            }
    }
    __syncthreads();

    // ---- 5 Horner stages: P = P*T2 + ce[s]*I + co[s]*T  (T2 frags cached) ----
    {
        const float ce[5] = { 2.48015873015873e-05f, 1.388888888888889e-03f,
                              4.1666666666666664e-02f, 0.5f, 1.0f };
        const float co[5] = { 2.7557319223985893e-06f, 1.984126984126984e-04f,
                              8.333333333333333e-03f, 1.6666666666666666e-01f, 1.0f };
        half8v t2h[2][2], t2l[2][2];
        #pragma unroll
        for (int b = 0; b < 2; ++b)
            #pragma unroll
            for (int ks = 0; ks < 2; ++ks) {
                t2h[b][ks] = frag16(Qh, wc + b, ks, lane);
                t2l[b][ks] = frag16(Ql, wc + b, ks, lane);
            }
        #pragma unroll
        for (int s = 0; s < 5; ++s) {
            half8v ah[2][2], al[2][2];
            #pragma unroll
            for (int a = 0; a < 2; ++a)
                #pragma unroll
                for (int ks = 0; ks < 2; ++ks) {
                    ah[a][ks] = frag16(Ph, wr + a, ks, lane);
                    al[a][ks] = frag16(Pl, wr + a, ks, lane);
                }
            f32x4 acc[2][2];
            #pragma unroll
            for (int a = 0; a < 2; ++a)
                #pragma unroll
                for (int b = 0; b < 2; ++b)
                    acc[a][b] = mm_split(ah[a], al[a], t2h[b], t2l[b]);
            __syncthreads();   // all waves done reading Ph/Pl
            const float fin = (s == 4) ? 0.5f : 1.0f;   // fold Q = P/2 into last stage
            #pragma unroll
            for (int a = 0; a < 2; ++a)
                #pragma unroll
                for (int b = 0; b < 2; ++b) {
                    const int rowp = (wc + b) * 16 + (lane & 15);
                    const int colp = (wr + a) * 16 + ((lane >> 4) << 2);
                    const half4v th = *reinterpret_cast<const half4v*>(Th + swz(rowp, colp * 2));
                    const half4v tl = *reinterpret_cast<const half4v*>(Tl + swz(rowp, colp * 2));
                    half4v h, l;
                    #pragma unroll
                    for (int e = 0; e < 4; ++e) {
                        const int grow = colp + e;        // element's C row
                        const int gcol = rowp;            // element's C col
                        const float tval = (float)th[e] + (float)tl[e] * (1.0f / 2048.0f);
                        const float v = (acc[a][b][e] + co[s] * tval
                                         + ((grow == gcol) ? ce[s] : 0.0f)) * fin;
                        Split sp = split16(v);
                        h[e] = sp.h; l[e] = sp.l;
                    }
                    *reinterpret_cast<half4v*>(Ph + swz(rowp, colp * 2)) = h;
                    *reinterpret_cast<half4v*>(Pl + swz(rowp, colp * 2)) = l;
                }
            __syncthreads();
        }
    }

    // ---- 4 squarings: Q = Q*Q ----
    #pragma unroll
    for (int s = 0; s < 4; ++s) {
        half8v ah[2][2], al[2][2], bh[2][2], bl[2][2];
        #pragma unroll
        for (int a = 0; a < 2; ++a)
            #pragma unroll
            for (int ks = 0; ks < 2; ++ks) {
                ah[a][ks] = frag16(Ph, wr + a, ks, lane);
                al[a][ks] = frag16(Pl, wr + a, ks, lane);
                bh[a][ks] = frag16(Ph, wc + a, ks, lane);
                bl[a][ks] = frag16(Pl, wc + a, ks, lane);
            }
        f32x4 acc[2][2];
        #pragma unroll
        for (int a = 0; a < 2; ++a)
            #pragma unroll
            for (int b = 0; b < 2; ++b)
                acc[a][b] = mm_split(ah[a], al[a], bh[b], bl[b]);
        __syncthreads();
        #pragma unroll
        for (int a = 0; a < 2; ++a)
            #pragma unroll
            for (int b = 0; b < 2; ++b) {
                const int rowp = (wc + b) * 16 + (lane & 15);
                const int colp = (wr + a) * 16 + ((lane >> 4) << 2);
                half4v h, l;
                #pragma unroll
                for (int e = 0; e < 4; ++e) {
                    Split sp = split16(acc[a][b][e]);
                    h[e] = sp.h; l[e] = sp.l;
                }
                *reinterpret_cast<half4v*>(Ph + swz(rowp, colp * 2)) = h;
                *reinterpret_cast<half4v*>(Pl + swz(rowp, colp * 2)) = l;
            }
        __syncthreads();
    }

    // ---- epilogue: out = (Qh + Ql/2048) * 65536, coalesced ----
    {
        const int r = t >> 2;
        const int cb0 = (t & 3) << 5;   // col byte base (col0 = (t&3)*16)
        const half8v h0 = *reinterpret_cast<const half8v*>(Ph + swz(r, cb0));
        const half8v h1 = *reinterpret_cast<const half8v*>(Ph + swz(r, cb0 + 16));
        const half8v l0 = *reinterpret_cast<const half8v*>(Pl + swz(r, cb0));
        const half8v l1 = *reinterpret_cast<const half8v*>(Pl + swz(r, cb0 + 16));
        float4* dst = reinterpret_cast<float4*>(out + base + r * 64 + ((t & 3) << 4));
        float v[16];
        #pragma unroll
        for (int e = 0; e < 8; ++e) {
            v[e]     = ((float)h0[e] + (float)l0[e] * (1.0f / 2048.0f)) * 65536.0f;
            v[8 + e] = ((float)h1[e] + (float)l1[e] * (1.0f / 2048.0f)) * 65536.0f;
        }
        #pragma unroll
        for (int q = 0; q < 4; ++q) {
            float4 o = { v[q * 4], v[q * 4 + 1], v[q * 4 + 2], v[q * 4 + 3] };
            dst[q] = o;
        }
    }
}

extern "C" void kernel_launch(void* const* d_in, const int* in_sizes, int n_in,
                              void* d_out, int out_size, void* d_ws, size_t ws_size,
                              hipStream_t stream) {
    const float* X = (const float*)d_in[0];
    float* out = (float*)d_out;
    const int batch = in_sizes[0] / (N * N);   // 8192
    expm64_kernel<<<dim3(batch), dim3(256), 0, stream>>>(X, out);
}

// Round 8
// 313.180 us; speedup vs baseline: 2.9466x; 1.1296x over previous
//
#include <hip/hip_runtime.h>

// Batched expm of symmetrized 64x64 fp32 matrices via scaling-and-squaring
// (s=4, degree-11 Taylor, Paterson-Stockmeyer chunk-2), matmuls on the MFMA
// pipe via fp16 2-way-split emulation of fp32:
//   x = hi + lo/2048 (hi RTZ-rounded fp16, lo fp16 of residual*2048)
//   A*B ~= Ah*Bh + (Ah*Bl' + Al'*Bh)/2048        (6 MFMAs/tile;
//   the Al'*Bl'/2048^2 term is ~2^-22 relative — below fp32 accum noise)
// All operands are symmetric (polynomials in T):
//   - B-fragment == A-fragment read pattern (contiguous ds_read_b128)
//   - intermediate C tiles written TRANSPOSED to LDS => contiguous writes
// fp16 planes [64][64] XOR-swizzled: byte ^= (row&7)<<4 (bank-conflict fix).
// Range: last Taylor stage folds *0.5 => Q=P/2; out = Q^16 * 65536.
// Final squaring stores f32 directly to global (no LDS round-trip).

typedef _Float16 half2v __attribute__((ext_vector_type(2)));
typedef _Float16 half4v __attribute__((ext_vector_type(4)));
typedef _Float16 half8v __attribute__((ext_vector_type(8)));
typedef float f32x4 __attribute__((ext_vector_type(4)));

constexpr int N = 64;

__device__ __forceinline__ void split2(float v0, float v1, half2v& h, half2v& l) {
    h = __builtin_bit_cast(half2v, __builtin_amdgcn_cvt_pkrtz(v0, v1));
    l = __builtin_bit_cast(half2v, __builtin_amdgcn_cvt_pkrtz((v0 - (float)h[0]) * 2048.0f,
                                                              (v1 - (float)h[1]) * 2048.0f));
}

__device__ __forceinline__ void split4(float v0, float v1, float v2, float v3,
                                       half4v& h, half4v& l) {
    half2v h01, l01, h23, l23;
    split2(v0, v1, h01, l01);
    split2(v2, v3, h23, l23);
    h[0] = h01[0]; h[1] = h01[1]; h[2] = h23[0]; h[3] = h23[1];
    l[0] = l01[0]; l[1] = l01[1]; l[2] = l23[0]; l[3] = l23[1];
}

__device__ __forceinline__ int swz(int row, int colbyte) {
    return (row * 128 + colbyte) ^ ((row & 7) << 4);
}

// A-frag (and, by symmetry, B-frag): lane reads M[tile*16 + lane%16][k0..k0+7],
// k0 = ks*32 + (lane/16)*8  -> one 16B ds_read_b128 (swizzled).
__device__ __forceinline__ half8v frag16(const char* p, int tile, int ks, int lane) {
    const int row = tile * 16 + (lane & 15);
    const int cb = (ks * 32 + ((lane >> 4) << 3)) * 2;
    return *reinterpret_cast<const half8v*>(p + swz(row, cb));
}

// 6-MFMA split product over K=64 (2 ksteps) for one 16x16 C tile.
__device__ __forceinline__ f32x4 mm_split(const half8v* ah, const half8v* al,
                                          const half8v* bh, const half8v* bl) {
    f32x4 c = {0.f, 0.f, 0.f, 0.f};
    c = __builtin_amdgcn_mfma_f32_16x16x32_f16(al[0], bh[0], c, 0, 0, 0);  // cross (x2^11)
    c = __builtin_amdgcn_mfma_f32_16x16x32_f16(al[1], bh[1], c, 0, 0, 0);
    c = __builtin_amdgcn_mfma_f32_16x16x32_f16(ah[0], bl[0], c, 0, 0, 0);
    c = __builtin_amdgcn_mfma_f32_16x16x32_f16(ah[1], bl[1], c, 0, 0, 0);
    #pragma unroll
    for (int e = 0; e < 4; ++e) c[e] *= (1.0f / 2048.0f);                  // -> 1
    c = __builtin_amdgcn_mfma_f32_16x16x32_f16(ah[0], bh[0], c, 0, 0, 0);  // hi*hi
    c = __builtin_amdgcn_mfma_f32_16x16x32_f16(ah[1], bh[1], c, 0, 0, 0);
    return c;
}

__global__ __launch_bounds__(256, 3) void expm64_kernel(const float* __restrict__ X,
                                                        float* __restrict__ out) {
    __shared__ alignas(16) char lds[49152];
    char* Th = lds;            // T hi plane   (8 KB each)
    char* Tl = lds + 8192;     // T lo
    char* Ph = lds + 16384;    // P hi
    char* Pl = lds + 24576;    // P lo
    char* Qh = lds + 32768;    // T2 hi
    char* Ql = lds + 40960;    // T2 lo
    float* Xs = reinterpret_cast<float*>(lds + 16384);  // fp32 X staging over Ph/Pl

    const int t = threadIdx.x;
    const int lane = t & 63;
    const int wv = t >> 6;          // wave 0..3
    const int wr = (wv >> 1) << 1;  // rowtile base (0 or 2)
    const int wc = (wv & 1) << 1;   // coltile base (0 or 2)
    const size_t base = (size_t)blockIdx.x * (N * N);

    // ---- load X (fp32) coalesced into staging ----
    {
        const float4* src = reinterpret_cast<const float4*>(X + base);
        float4* dst = reinterpret_cast<float4*>(Xs);
        #pragma unroll
        for (int i = 0; i < 4; ++i) dst[t + 256 * i] = src[t + 256 * i];
    }
    __syncthreads();

    const int r0 = (t >> 4) << 2;
    const int c0 = (t & 15) << 2;

    // ---- T = (X + X^T)/32, split -> Th/Tl; keep fp32 in regs ----
    float tv[4][4];
    #pragma unroll
    for (int i = 0; i < 4; ++i) {
        #pragma unroll
        for (int j = 0; j < 4; ++j)
            tv[i][j] = (Xs[(r0 + i) * 64 + (c0 + j)] + Xs[(c0 + j) * 64 + (r0 + i)]) * (1.0f / 32.0f);
        half4v h, l;
        split4(tv[i][0], tv[i][1], tv[i][2], tv[i][3], h, l);
        *reinterpret_cast<half4v*>(Th + swz(r0 + i, c0 * 2)) = h;
        *reinterpret_cast<half4v*>(Tl + swz(r0 + i, c0 * 2)) = l;
    }
    __syncthreads();   // X consumed, T planes complete

    // ---- P0 = c10*I + c11*T -> Ph/Pl (overwrites X staging) ----
    {
        const float c10 = 2.755731922398589e-07f;   // 1/10!
        const float c11 = 2.505210838544172e-08f;   // 1/11!
        #pragma unroll
        for (int i = 0; i < 4; ++i) {
            float v[4];
            #pragma unroll
            for (int j = 0; j < 4; ++j)
                v[j] = c11 * tv[i][j] + ((r0 + i == c0 + j) ? c10 : 0.0f);
            half4v h, l;
            split4(v[0], v[1], v[2], v[3], h, l);
            *reinterpret_cast<half4v*>(Ph + swz(r0 + i, c0 * 2)) = h;
            *reinterpret_cast<half4v*>(Pl + swz(r0 + i, c0 * 2)) = l;
        }
    }
    __syncthreads();

    // ---- stage 1: T2 = T*T  -> Qh/Ql (write arena != read arena: 1 barrier) ----
    {
        half8v ah[2][2], al[2][2], bh[2][2], bl[2][2];
        #pragma unroll
        for (int a = 0; a < 2; ++a)
            #pragma unroll
            for (int ks = 0; ks < 2; ++ks) {
                ah[a][ks] = frag16(Th, wr + a, ks, lane);
                al[a][ks] = frag16(Tl, wr + a, ks, lane);
                bh[a][ks] = frag16(Th, wc + a, ks, lane);
                bl[a][ks] = frag16(Tl, wc + a, ks, lane);
            }
        #pragma unroll
        for (int a = 0; a < 2; ++a)
            #pragma unroll
            for (int b = 0; b < 2; ++b) {
                f32x4 acc = mm_split(ah[a], al[a], bh[b], bl[b]);
                const int rowp = (wc + b) * 16 + (lane & 15);          // transposed
                const int colp = (wr + a) * 16 + ((lane >> 4) << 2);
                half4v h, l;
                split4(acc[0], acc[1], acc[2], acc[3], h, l);
                *reinterpret_cast<half4v*>(Qh + swz(rowp, colp * 2)) = h;
                *reinterpret_cast<half4v*>(Ql + swz(rowp, colp * 2)) = l;
            }
    }
    __syncthreads();

    // ---- 5 Horner stages: P = P*T2 + ce[s]*I + co[s]*T  (T2 frags cached) ----
    {
        const float ce[5] = { 2.48015873015873e-05f, 1.388888888888889e-03f,
                              4.1666666666666664e-02f, 0.5f, 1.0f };
        const float co[5] = { 2.7557319223985893e-06f, 1.984126984126984e-04f,
                              8.333333333333333e-03f, 1.6666666666666666e-01f, 1.0f };
        half8v t2h[2][2], t2l[2][2];
        #pragma unroll
        for (int b = 0; b < 2; ++b)
            #pragma unroll
            for (int ks = 0; ks < 2; ++ks) {
                t2h[b][ks] = frag16(Qh, wc + b, ks, lane);
                t2l[b][ks] = frag16(Ql, wc + b, ks, lane);
            }
        #pragma unroll
        for (int s = 0; s < 5; ++s) {
            half8v ah[2][2], al[2][2];
            #pragma unroll
            for (int a = 0; a < 2; ++a)
                #pragma unroll
                for (int ks = 0; ks < 2; ++ks) {
                    ah[a][ks] = frag16(Ph, wr + a, ks, lane);
                    al[a][ks] = frag16(Pl, wr + a, ks, lane);
                }
            f32x4 acc[2][2];
            #pragma unroll
            for (int a = 0; a < 2; ++a)
                #pragma unroll
                for (int b = 0; b < 2; ++b)
                    acc[a][b] = mm_split(ah[a], al[a], t2h[b], t2l[b]);
            __syncthreads();   // all waves done reading Ph/Pl
            const float fin = (s == 4) ? 0.5f : 1.0f;   // fold Q = P/2 into last stage
            #pragma unroll
            for (int a = 0; a < 2; ++a)
                #pragma unroll
                for (int b = 0; b < 2; ++b) {
                    const int rowp = (wc + b) * 16 + (lane & 15);
                    const int colp = (wr + a) * 16 + ((lane >> 4) << 2);
                    const half4v th = *reinterpret_cast<const half4v*>(Th + swz(rowp, colp * 2));
                    const half4v tl = *reinterpret_cast<const half4v*>(Tl + swz(rowp, colp * 2));
                    float v[4];
                    #pragma unroll
                    for (int e = 0; e < 4; ++e) {
                        const int grow = colp + e;        // element's C row
                        const int gcol = rowp;            // element's C col
                        const float tval = (float)th[e] + (float)tl[e] * (1.0f / 2048.0f);
                        v[e] = (acc[a][b][e] + co[s] * tval
                                + ((grow == gcol) ? ce[s] : 0.0f)) * fin;
                    }
                    half4v h, l;
                    split4(v[0], v[1], v[2], v[3], h, l);
                    *reinterpret_cast<half4v*>(Ph + swz(rowp, colp * 2)) = h;
                    *reinterpret_cast<half4v*>(Pl + swz(rowp, colp * 2)) = l;
                }
            __syncthreads();
        }
    }

    // ---- 4 squarings: Q = Q*Q; last one stores f32 directly to global ----
    #pragma unroll
    for (int s = 0; s < 4; ++s) {
        half8v ah[2][2], al[2][2], bh[2][2], bl[2][2];
        #pragma unroll
        for (int a = 0; a < 2; ++a)
            #pragma unroll
            for (int ks = 0; ks < 2; ++ks) {
                ah[a][ks] = frag16(Ph, wr + a, ks, lane);
                al[a][ks] = frag16(Pl, wr + a, ks, lane);
                bh[a][ks] = frag16(Ph, wc + a, ks, lane);
                bl[a][ks] = frag16(Pl, wc + a, ks, lane);
            }
        f32x4 acc[2][2];
        #pragma unroll
        for (int a = 0; a < 2; ++a)
            #pragma unroll
            for (int b = 0; b < 2; ++b)
                acc[a][b] = mm_split(ah[a], al[a], bh[b], bl[b]);
        if (s < 3) {
            __syncthreads();
            #pragma unroll
            for (int a = 0; a < 2; ++a)
                #pragma unroll
                for (int b = 0; b < 2; ++b) {
                    const int rowp = (wc + b) * 16 + (lane & 15);
                    const int colp = (wr + a) * 16 + ((lane >> 4) << 2);
                    half4v h, l;
                    split4(acc[a][b][0], acc[a][b][1], acc[a][b][2], acc[a][b][3], h, l);
                    *reinterpret_cast<half4v*>(Ph + swz(rowp, colp * 2)) = h;
                    *reinterpret_cast<half4v*>(Pl + swz(rowp, colp * 2)) = l;
                }
            __syncthreads();
        } else {
            // direct untransposed store: C[row][col], row from A-tile, col from B-tile.
            float* o = out + base;
            #pragma unroll
            for (int a = 0; a < 2; ++a)
                #pragma unroll
                for (int b = 0; b < 2; ++b) {
                    const int row0 = (wr + a) * 16 + ((lane >> 4) << 2);
                    const int col  = (wc + b) * 16 + (lane & 15);
                    #pragma unroll
                    for (int e = 0; e < 4; ++e)
                        o[(row0 + e) * 64 + col] = acc[a][b][e] * 65536.0f;
                }
        }
    }
}

extern "C" void kernel_launch(void* const* d_in, const int* in_sizes, int n_in,
                              void* d_out, int out_size, void* d_ws, size_t ws_size,
                              hipStream_t stream) {
    const float* X = (const float*)d_in[0];
    float* out = (float*)d_out;
    const int batch = in_sizes[0] / (N * N);   // 8192
    expm64_kernel<<<dim3(batch), dim3(256), 0, stream>>>(X, out);
}